// Round 14
// baseline (206.885 us; speedup 1.0000x reference)
//
#include <hip/hip_runtime.h>

#define NTH 256   // 4 waves; 16 rows/block; grid 512 -> 2 independent blocks/CU

typedef _Float16 half8 __attribute__((ext_vector_type(8)));
typedef _Float16 half4 __attribute__((ext_vector_type(4)));
typedef __attribute__((ext_vector_type(4))) float floatx4;

__device__ __forceinline__ float fast_sigmoid(float x) {
    return __builtin_amdgcn_rcpf(1.f + __expf(-x));
}
__device__ __forceinline__ float fast_tanh(float x) {
    return fmaf(-2.f, __builtin_amdgcn_rcpf(__expf(2.f * x) + 1.f), 1.f);
}

#define MFMA16 __builtin_amdgcn_mfma_f32_16x16x32_f16

// ---------------------------------------------------------------------------
// Encoder layer: [16,128] (LDS) @ W[128,128] + bias -> [16,128] (LDS)
// ---------------------------------------------------------------------------
template<bool RELU>
__device__ __forceinline__ void mlp_layer(const float (*in)[132],
                                          const float* __restrict__ W,
                                          const float* __restrict__ bias,
                                          float (*outl)[132], int c, int g) {
    float acc[8];
    #pragma unroll
    for (int i = 0; i < 8; i++) acc[i] = 0.f;
    for (int k = 0; k < 128; k += 4) {
        float w0 = W[(k + 0) * 128 + c];
        float w1 = W[(k + 1) * 128 + c];
        float w2 = W[(k + 2) * 128 + c];
        float w3 = W[(k + 3) * 128 + c];
        #pragma unroll
        for (int i = 0; i < 8; i++) {
            const float4 xv = *(const float4*)&in[g * 8 + i][k];
            acc[i] = fmaf(xv.x, w0, fmaf(xv.y, w1, fmaf(xv.z, w2, fmaf(xv.w, w3, acc[i]))));
        }
    }
    const float bv = bias[c];
    #pragma unroll
    for (int i = 0; i < 8; i++) {
        float v = acc[i] + bv;
        outl[g * 8 + i][c] = RELU ? fmaxf(v, 0.f) : v;
    }
}

// ---------------------------------------------------------------------------
// Fused encoder + 50-iter GRU (single-pass f16 MFMA, SWAPPED operands:
// A = weights (M = gate cols), B = h (N = batch rows)) + per-wave decoder.
// C-layout: lane (quad,l15) holds C[col=quad*4+reg][row=l15] -> contiguous
// col writes (ds_write_b64), scalar xp per lane, 2-stage decoder reduce.
// 16 rows/block, 4 waves; wave w owns gate cols {g*128 + w*32 + nt*16 + ...}.
// ---------------------------------------------------------------------------
__global__ __launch_bounds__(NTH, 2)
void gru_fused_kernel(const float* __restrict__ x,
                      const float* __restrict__ ew0, const float* __restrict__ eb0,
                      const float* __restrict__ ew1, const float* __restrict__ eb1,
                      const float* __restrict__ ew2, const float* __restrict__ eb2,
                      const float* __restrict__ w_ih, const float* __restrict__ w_hh,
                      const float* __restrict__ b_ih, const float* __restrict__ b_hh,
                      const float* __restrict__ dw0, const float* __restrict__ db0,
                      const float* __restrict__ dw1, const float* __restrict__ db1,
                      float* __restrict__ out) {
    __shared__ float hA[16][132];                        // encoder staging
    __shared__ float smemB[16 * 132];                    // encoder ping buffer
    __shared__ __align__(16) _Float16 h16[2][16][136];   // f16 h planes (dbuf)
    __shared__ float outb[16][52];

    const int tid  = threadIdx.x;
    const int b0   = blockIdx.x * 16;
    const int lane = tid & 63;
    const int w    = tid >> 6;     // wave 0..3
    const int quad = lane >> 4;
    const int l15  = lane & 15;

    // ---------------- encoder: x -> hA ----------------
    {
        const int c = tid & 127;
        const int g = tid >> 7;    // 0..1, 8 rows each
        float acc[8];
        #pragma unroll
        for (int i = 0; i < 8; i++) acc[i] = 0.f;
        for (int k = 0; k < 256; k += 4) {
            float w0 = ew0[(k + 0) * 128 + c];
            float w1 = ew0[(k + 1) * 128 + c];
            float w2 = ew0[(k + 2) * 128 + c];
            float w3 = ew0[(k + 3) * 128 + c];
            #pragma unroll
            for (int i = 0; i < 8; i++) {
                const float4 xv = *(const float4*)(x + (size_t)(b0 + g * 8 + i) * 256 + k);
                acc[i] = fmaf(xv.x, w0, fmaf(xv.y, w1, fmaf(xv.z, w2, fmaf(xv.w, w3, acc[i]))));
            }
        }
        float bv = eb0[c];
        #pragma unroll
        for (int i = 0; i < 8; i++) hA[g * 8 + i][c] = fmaxf(acc[i] + bv, 0.f);
        __syncthreads();
        mlp_layer<true>(hA, ew1, eb1, (float(*)[132])smemB, c, g);
        __syncthreads();
        mlp_layer<false>((float(*)[132])smemB, ew2, eb2, hA, c, g);
        __syncthreads();
    }

    // ---------------- persistent register weights (f16, A-operand) --------
    // A-frag for gate g, nt: lane holds A[m=l15][k=quad*8+e], m-col = g*128+w*32+nt*16+l15
    half8 wb16[3][2][4];
    #pragma unroll
    for (int g = 0; g < 3; g++)
        #pragma unroll
        for (int nt = 0; nt < 2; nt++) {
            const float* wrow = w_hh + (g * 128 + w * 32 + nt * 16 + l15) * 128;
            #pragma unroll
            for (int kt = 0; kt < 4; kt++) {
                const int kb = kt * 32 + quad * 8;
                half8 hv;
                #pragma unroll
                for (int e = 0; e < 8; e++) hv[e] = (_Float16)wrow[kb + e];
                wb16[g][nt][kt] = hv;
            }
        }
    half8 dw16[4];   // A-frag of dw0^T: lane holds dw0[k=quad*8+e][out=l15]
    #pragma unroll
    for (int kt = 0; kt < 4; kt++) {
        half8 hv;
        #pragma unroll
        for (int e = 0; e < 8; e++)
            hv[e] = (_Float16)dw0[(kt * 32 + quad * 8 + e) * 16 + l15];
        dw16[kt] = hv;
    }
    // gate constants for this lane's 8 cols: col = w*32 + nt*16 + quad*4 + r
    float bs_r[2][4], bs_z[2][4], bihn[2][4], bhhn[2][4];
    float wih0[2][4], wih1[2][4], wih2[2][4];
    #pragma unroll
    for (int nt = 0; nt < 2; nt++)
        #pragma unroll
        for (int r = 0; r < 4; r++) {
            const int col = w * 32 + nt * 16 + quad * 4 + r;
            wih0[nt][r] = w_ih[col];
            wih1[nt][r] = w_ih[128 + col];
            wih2[nt][r] = w_ih[256 + col];
            bs_r[nt][r] = b_ih[col] + b_hh[col];
            bs_z[nt][r] = b_ih[128 + col] + b_hh[128 + col];
            bihn[nt][r] = b_ih[256 + col];
            bhhn[nt][r] = b_hh[256 + col];
        }
    float db0v[4], dw1v[4];
    #pragma unroll
    for (int r = 0; r < 4; r++) {
        db0v[r] = db0[quad * 4 + r];
        dw1v[r] = dw1[quad * 4 + r];
    }
    const float db1r = db1[0];

    // ---------------- init planes[0] + lane-private fp32 h ----------------
    for (int i = tid; i < 16 * 128; i += NTH) {
        const int b = i >> 7, j = i & 127;
        h16[0][b][j] = (_Float16)hA[b][j];
    }
    if (tid < 16) outb[tid][0] = 0.f;
    float hold[8];   // h[row l15][col w*32+nt*16+quad*4+r]
    #pragma unroll
    for (int nt = 0; nt < 2; nt++)
        #pragma unroll
        for (int r = 0; r < 4; r++)
            hold[nt * 4 + r] = hA[l15][w * 32 + nt * 16 + quad * 4 + r];
    __syncthreads();

    // ---------------- 50 iterations: dec(h_t) -> out[t]; gates -> h_{t+1} ---
    for (int t = 0; t <= 49; t++) {
        const int cur = t & 1, nxt = cur ^ 1;

        // B-frags of h (4 b128; single drain): B[k=quad*8+e][n=l15]
        half8 ah[4];
        #pragma unroll
        for (int kt = 0; kt < 4; kt++)
            ah[kt] = *(const half8*)&h16[cur][l15][kt * 32 + quad * 8];

        // decoder: d[out=quad*4+r][row=l15]
        floatx4 dacc = (floatx4){0.f, 0.f, 0.f, 0.f};
        #pragma unroll
        for (int kt = 0; kt < 4; kt++)
            dacc = MFMA16(dw16[kt], ah[kt], dacc, 0, 0, 0);

        // GRU: acc[g][nt] -> gh[col=quad*4+r + 16nt + 32w + 128g][row=l15]
        floatx4 acc[3][2];
        #pragma unroll
        for (int g = 0; g < 3; g++)
            #pragma unroll
            for (int nt = 0; nt < 2; nt++) acc[g][nt] = (floatx4){0.f, 0.f, 0.f, 0.f};
        #pragma unroll
        for (int kt = 0; kt < 4; kt++)
            #pragma unroll
            for (int g = 0; g < 3; g++) {
                acc[g][0] = MFMA16(wb16[g][0][kt], ah[kt], acc[g][0], 0, 0, 0);
                acc[g][1] = MFMA16(wb16[g][1][kt], ah[kt], acc[g][1], 0, 0, 0);
            }

        // decoder reduce: in-lane over 4 outs, then cross-quad (lanes +-16,32)
        float s = 0.f;
        #pragma unroll
        for (int r = 0; r < 4; r++)
            s = fmaf(fmaxf(dacc[r] + db0v[r], 0.f), dw1v[r], s);
        s += __shfl_xor(s, 16, 64);
        s += __shfl_xor(s, 32, 64);
        const float xp = (t == 0) ? 0.f : (s + db1r);   // scalar: row l15's input
        if (t > 0 && w == 0 && quad == 0)
            outb[l15][t] = xp;

        // gates -> h_{t+1}; writes are 4 contiguous cols -> ds_write_b64
        if (t < 49) {
            #pragma unroll
            for (int nt = 0; nt < 2; nt++) {
                half4 hv;
                #pragma unroll
                for (int r = 0; r < 4; r++) {
                    float gr  = fmaf(xp, wih0[nt][r], acc[0][nt][r] + bs_r[nt][r]);
                    float gz  = fmaf(xp, wih1[nt][r], acc[1][nt][r] + bs_z[nt][r]);
                    float ghn = acc[2][nt][r] + bhhn[nt][r];
                    float gxn = fmaf(xp, wih2[nt][r], bihn[nt][r]);
                    float rg = fast_sigmoid(gr);
                    float zg = fast_sigmoid(gz);
                    float ng = fast_tanh(fmaf(rg, ghn, gxn));
                    const float hn = fmaf(zg, hold[nt * 4 + r] - ng, ng);
                    hold[nt * 4 + r] = hn;
                    hv[r] = (_Float16)hn;
                }
                *(half4*)&h16[nxt][l15][w * 32 + nt * 16 + quad * 4] = hv;
            }
        }
        __syncthreads();   // planes[nxt] complete; outb[t] visible
    }

    // coalesced output write: [16 rows][50 cols], col 0 = 0
    for (int e = tid; e < 16 * 50; e += NTH) {
        const int b = e / 50;
        const int t = e - b * 50;
        out[(size_t)b0 * 50 + e] = outb[b][t];
    }
}

// ---------------------------------------------------------------------------
extern "C" void kernel_launch(void* const* d_in, const int* in_sizes, int n_in,
                              void* d_out, int out_size, void* d_ws, size_t ws_size,
                              hipStream_t stream) {
    const float* x   = (const float*)d_in[0];
    const float* ew0 = (const float*)d_in[1];
    const float* eb0 = (const float*)d_in[2];
    const float* ew1 = (const float*)d_in[3];
    const float* eb1 = (const float*)d_in[4];
    const float* ew2 = (const float*)d_in[5];
    const float* eb2 = (const float*)d_in[6];
    const float* wih = (const float*)d_in[7];
    const float* whh = (const float*)d_in[8];
    const float* bih = (const float*)d_in[9];
    const float* bhh = (const float*)d_in[10];
    const float* dw0 = (const float*)d_in[11];
    const float* db0 = (const float*)d_in[12];
    const float* dw1 = (const float*)d_in[13];
    const float* db1 = (const float*)d_in[14];
    float* out = (float*)d_out;

    gru_fused_kernel<<<512, NTH, 0, stream>>>(
        x, ew0, eb0, ew1, eb1, ew2, eb2, wih, whh, bih, bhh,
        dw0, db0, dw1, db1, out);
}

// Round 15
// 206.364 us; speedup vs baseline: 1.0025x; 1.0025x over previous
//
#include <hip/hip_runtime.h>

#define NTH 256   // 4 waves; 16 rows/block; grid 512 -> 2 independent blocks/CU

typedef _Float16 half8 __attribute__((ext_vector_type(8)));
typedef _Float16 half4 __attribute__((ext_vector_type(4)));
typedef __attribute__((ext_vector_type(4))) float floatx4;

__device__ __forceinline__ float fast_sigmoid(float x) {
    return __builtin_amdgcn_rcpf(1.f + __expf(-x));
}
__device__ __forceinline__ float fast_tanh(float x) {
    return fmaf(-2.f, __builtin_amdgcn_rcpf(__expf(2.f * x) + 1.f), 1.f);
}

#define MFMA16 __builtin_amdgcn_mfma_f32_16x16x32_f16

// ---------------------------------------------------------------------------
// Encoder layer: [16,128] (LDS) @ W[128,128] + bias -> [16,128] (LDS)
// ---------------------------------------------------------------------------
template<bool RELU>
__device__ __forceinline__ void mlp_layer(const float (*in)[132],
                                          const float* __restrict__ W,
                                          const float* __restrict__ bias,
                                          float (*outl)[132], int c, int g) {
    float acc[8];
    #pragma unroll
    for (int i = 0; i < 8; i++) acc[i] = 0.f;
    for (int k = 0; k < 128; k += 4) {
        float w0 = W[(k + 0) * 128 + c];
        float w1 = W[(k + 1) * 128 + c];
        float w2 = W[(k + 2) * 128 + c];
        float w3 = W[(k + 3) * 128 + c];
        #pragma unroll
        for (int i = 0; i < 8; i++) {
            const float4 xv = *(const float4*)&in[g * 8 + i][k];
            acc[i] = fmaf(xv.x, w0, fmaf(xv.y, w1, fmaf(xv.z, w2, fmaf(xv.w, w3, acc[i]))));
        }
    }
    const float bv = bias[c];
    #pragma unroll
    for (int i = 0; i < 8; i++) {
        float v = acc[i] + bv;
        outl[g * 8 + i][c] = RELU ? fmaxf(v, 0.f) : v;
    }
}

// ---------------------------------------------------------------------------
// Fused encoder + 50-iter GRU (single-pass f16 MFMA, A = weights, B = h) +
// per-wave decoder. C-layout: lane (quad,l15) holds C[col=quad*4+r][row=l15]
// -> contiguous col writes (ds_write_b64), scalar xp/lane, 2-stage reduce.
// Spill-free: nt-sequential acc, bias folded into MFMA C-init, f16-packed
// xp-coefficients. 16 rows/block, 4 waves, 2 blocks/CU.
// ---------------------------------------------------------------------------
__global__ __launch_bounds__(NTH, 2)
void gru_fused_kernel(const float* __restrict__ x,
                      const float* __restrict__ ew0, const float* __restrict__ eb0,
                      const float* __restrict__ ew1, const float* __restrict__ eb1,
                      const float* __restrict__ ew2, const float* __restrict__ eb2,
                      const float* __restrict__ w_ih, const float* __restrict__ w_hh,
                      const float* __restrict__ b_ih, const float* __restrict__ b_hh,
                      const float* __restrict__ dw0, const float* __restrict__ db0,
                      const float* __restrict__ dw1, const float* __restrict__ db1,
                      float* __restrict__ out) {
    __shared__ float hA[16][132];                        // encoder staging
    __shared__ float smemB[16 * 132];                    // encoder ping buffer
    __shared__ __align__(16) _Float16 h16[2][16][136];   // f16 h planes (dbuf)
    __shared__ float outb[16][52];

    const int tid  = threadIdx.x;
    const int b0   = blockIdx.x * 16;
    const int lane = tid & 63;
    const int w    = tid >> 6;     // wave 0..3
    const int quad = lane >> 4;
    const int l15  = lane & 15;

    // ---------------- encoder: x -> hA ----------------
    {
        const int c = tid & 127;
        const int g = tid >> 7;    // 0..1, 8 rows each
        float acc[8];
        #pragma unroll
        for (int i = 0; i < 8; i++) acc[i] = 0.f;
        for (int k = 0; k < 256; k += 4) {
            float w0 = ew0[(k + 0) * 128 + c];
            float w1 = ew0[(k + 1) * 128 + c];
            float w2 = ew0[(k + 2) * 128 + c];
            float w3 = ew0[(k + 3) * 128 + c];
            #pragma unroll
            for (int i = 0; i < 8; i++) {
                const float4 xv = *(const float4*)(x + (size_t)(b0 + g * 8 + i) * 256 + k);
                acc[i] = fmaf(xv.x, w0, fmaf(xv.y, w1, fmaf(xv.z, w2, fmaf(xv.w, w3, acc[i]))));
            }
        }
        float bv = eb0[c];
        #pragma unroll
        for (int i = 0; i < 8; i++) hA[g * 8 + i][c] = fmaxf(acc[i] + bv, 0.f);
        __syncthreads();
        mlp_layer<true>(hA, ew1, eb1, (float(*)[132])smemB, c, g);
        __syncthreads();
        mlp_layer<false>((float(*)[132])smemB, ew2, eb2, hA, c, g);
        __syncthreads();
    }

    // ---------------- persistent register weights (f16, A-operand) --------
    half8 wb16[3][2][4];
    #pragma unroll
    for (int g = 0; g < 3; g++)
        #pragma unroll
        for (int nt = 0; nt < 2; nt++) {
            const float* wrow = w_hh + (g * 128 + w * 32 + nt * 16 + l15) * 128;
            #pragma unroll
            for (int kt = 0; kt < 4; kt++) {
                const int kb = kt * 32 + quad * 8;
                half8 hv;
                #pragma unroll
                for (int e = 0; e < 8; e++) hv[e] = (_Float16)wrow[kb + e];
                wb16[g][nt][kt] = hv;
            }
        }
    half8 dw16[4];   // A-frag of dw0^T: lane holds dw0[k=quad*8+e][out=l15]
    #pragma unroll
    for (int kt = 0; kt < 4; kt++) {
        half8 hv;
        #pragma unroll
        for (int e = 0; e < 8; e++)
            hv[e] = (_Float16)dw0[(kt * 32 + quad * 8 + e) * 16 + l15];
        dw16[kt] = hv;
    }
    // gate constants for this lane's 8 cols (col = w*32 + nt*16 + quad*4 + r):
    // fp32 bias vectors double as MFMA C-init; xp-coefficients packed f16.
    floatx4 bias_r[2], bias_z[2], bias_n[2];
    half4 wih_h[3][2], bihn_h[2];
    #pragma unroll
    for (int nt = 0; nt < 2; nt++) {
        half4 w0v, w1v, w2v, bnv;
        #pragma unroll
        for (int r = 0; r < 4; r++) {
            const int col = w * 32 + nt * 16 + quad * 4 + r;
            bias_r[nt][r] = b_ih[col] + b_hh[col];
            bias_z[nt][r] = b_ih[128 + col] + b_hh[128 + col];
            bias_n[nt][r] = b_hh[256 + col];
            w0v[r] = (_Float16)w_ih[col];
            w1v[r] = (_Float16)w_ih[128 + col];
            w2v[r] = (_Float16)w_ih[256 + col];
            bnv[r] = (_Float16)b_ih[256 + col];
        }
        wih_h[0][nt] = w0v; wih_h[1][nt] = w1v; wih_h[2][nt] = w2v;
        bihn_h[nt] = bnv;
    }
    float db0v[4], dw1v[4];
    #pragma unroll
    for (int r = 0; r < 4; r++) {
        db0v[r] = db0[quad * 4 + r];
        dw1v[r] = dw1[quad * 4 + r];
    }
    const float db1r = db1[0];

    // ---------------- init planes[0] + lane-private fp32 h ----------------
    for (int i = tid; i < 16 * 128; i += NTH) {
        const int b = i >> 7, j = i & 127;
        h16[0][b][j] = (_Float16)hA[b][j];
    }
    if (tid < 16) outb[tid][0] = 0.f;
    float hold[8];   // h[row l15][col w*32+nt*16+quad*4+r]
    #pragma unroll
    for (int nt = 0; nt < 2; nt++)
        #pragma unroll
        for (int r = 0; r < 4; r++)
            hold[nt * 4 + r] = hA[l15][w * 32 + nt * 16 + quad * 4 + r];
    __syncthreads();

    // ---------------- 50 iterations: dec(h_t) -> out[t]; gates -> h_{t+1} ---
    for (int t = 0; t <= 49; t++) {
        const int cur = t & 1, nxt = cur ^ 1;

        // B-frags of h (4 b128; single drain): B[k=quad*8+e][n=l15]
        half8 ah[4];
        #pragma unroll
        for (int kt = 0; kt < 4; kt++)
            ah[kt] = *(const half8*)&h16[cur][l15][kt * 32 + quad * 8];

        // decoder: d[out=quad*4+r][row=l15]
        floatx4 dacc = (floatx4){0.f, 0.f, 0.f, 0.f};
        #pragma unroll
        for (int kt = 0; kt < 4; kt++)
            dacc = MFMA16(dw16[kt], ah[kt], dacc, 0, 0, 0);

        // decoder reduce: in-lane over 4 outs, then cross-quad
        float s = 0.f;
        #pragma unroll
        for (int r = 0; r < 4; r++)
            s = fmaf(fmaxf(dacc[r] + db0v[r], 0.f), dw1v[r], s);
        s += __shfl_xor(s, 16, 64);
        s += __shfl_xor(s, 32, 64);
        const float xp = (t == 0) ? 0.f : (s + db1r);   // row l15's input
        if (t > 0 && w == 0 && quad == 0)
            outb[l15][t] = xp;

        // GRU + gates, nt-sequential (acc regs halved; VALU/MFMA interleave)
        if (t < 49) {
            #pragma unroll
            for (int nt = 0; nt < 2; nt++) {
                floatx4 a0 = bias_r[nt], a1 = bias_z[nt], a2 = bias_n[nt];
                #pragma unroll
                for (int kt = 0; kt < 4; kt++) {
                    a0 = MFMA16(wb16[0][nt][kt], ah[kt], a0, 0, 0, 0);
                    a1 = MFMA16(wb16[1][nt][kt], ah[kt], a1, 0, 0, 0);
                    a2 = MFMA16(wb16[2][nt][kt], ah[kt], a2, 0, 0, 0);
                }
                half4 hv;
                #pragma unroll
                for (int r = 0; r < 4; r++) {
                    float gr  = fmaf(xp, (float)wih_h[0][nt][r], a0[r]);
                    float gz  = fmaf(xp, (float)wih_h[1][nt][r], a1[r]);
                    float gxn = fmaf(xp, (float)wih_h[2][nt][r], (float)bihn_h[nt][r]);
                    float rg = fast_sigmoid(gr);
                    float zg = fast_sigmoid(gz);
                    float ng = fast_tanh(fmaf(rg, a2[r], gxn));
                    const float hn = fmaf(zg, hold[nt * 4 + r] - ng, ng);
                    hold[nt * 4 + r] = hn;
                    hv[r] = (_Float16)hn;
                }
                *(half4*)&h16[nxt][l15][w * 32 + nt * 16 + quad * 4] = hv;
            }
        }
        __syncthreads();   // planes[nxt] complete; outb[t] visible
    }

    // coalesced output write: [16 rows][50 cols], col 0 = 0
    for (int e = tid; e < 16 * 50; e += NTH) {
        const int b = e / 50;
        const int t = e - b * 50;
        out[(size_t)b0 * 50 + e] = outb[b][t];
    }
}

// ---------------------------------------------------------------------------
extern "C" void kernel_launch(void* const* d_in, const int* in_sizes, int n_in,
                              void* d_out, int out_size, void* d_ws, size_t ws_size,
                              hipStream_t stream) {
    const float* x   = (const float*)d_in[0];
    const float* ew0 = (const float*)d_in[1];
    const float* eb0 = (const float*)d_in[2];
    const float* ew1 = (const float*)d_in[3];
    const float* eb1 = (const float*)d_in[4];
    const float* ew2 = (const float*)d_in[5];
    const float* eb2 = (const float*)d_in[6];
    const float* wih = (const float*)d_in[7];
    const float* whh = (const float*)d_in[8];
    const float* bih = (const float*)d_in[9];
    const float* bhh = (const float*)d_in[10];
    const float* dw0 = (const float*)d_in[11];
    const float* db0 = (const float*)d_in[12];
    const float* dw1 = (const float*)d_in[13];
    const float* db1 = (const float*)d_in[14];
    float* out = (float*)d_out;

    gru_fused_kernel<<<512, NTH, 0, stream>>>(
        x, ew0, eb0, ew1, eb1, ew2, eb2, wih, whh, bih, bhh,
        dw0, db0, dw1, db1, out);
}